// Round 1
// 1260.390 us; speedup vs baseline: 1.0070x; 1.0070x over previous
//
#include <hip/hip_runtime.h>
#include <math.h>

#define T_LEN 8192
#define NUM_CH 64
#define HID 256
#define NUM_CLS 40
#define NUM_PROP 1024
#define NUM_PROP_AFTER 256
#define PROP_LEN 128

#define MS 4        // sequences per group
#define NGRP 64     // sequence groups (NUM_PROP_AFTER / MS)
#define NSL 4       // hidden slices (64 units each)
#define KH 320      // K in halves: 256 h + 64 x
#define KSEGN 4     // K segments per row
#define SEGH 80     // halves per segment

typedef _Float16 h2_t __attribute__((ext_vector_type(2)));
union U32H2 { unsigned int u; h2_t h; };
union HU16 { _Float16 h; unsigned short u; };

#if defined(__has_builtin)
#if __has_builtin(__builtin_amdgcn_fdot2)
#define HAS_FDOT2 1
#endif
#endif

__device__ __forceinline__ float dot2f(unsigned int wa, unsigned int hb, float acc) {
    U32H2 a, b;
    a.u = wa;
    b.u = hb;
#ifdef HAS_FDOT2
    return __builtin_amdgcn_fdot2(a.h, b.h, acc, false);
#else
    return acc + (float)a.h[0] * (float)b.h[0] + (float)a.h[1] * (float)b.h[1];
#endif
}

__device__ __forceinline__ float dot8f(const uint4& w, const uint4& h, float acc) {
    acc = dot2f(w.x, h.x, acc);
    acc = dot2f(w.y, h.y, acc);
    acc = dot2f(w.z, h.z, acc);
    acc = dot2f(w.w, h.w, acc);
    return acc;
}

__device__ __forceinline__ float fsigmoid(float x) { return 1.0f / (1.0f + __expf(-x)); }
__device__ __forceinline__ float ftanh(float x) {
    float e = __expf(-2.0f * fabsf(x));
    float t = (1.0f - e) / (1.0f + e);
    return copysignf(t, x);
}

// ---------------------------------------------------------------------------
// Pack W into f16, per-(slice,kseg) register-fragment layout:
// uint4 index = ((s*4 + kseg)*10 + j)*256 + row_local   (row_local = gate*64+unit)
// half e8 in uint4 covers kh = kseg*80 + j*8 + e8; kh<256 -> W_hh, else W_ih.
// Also zeroes the per-group sync counters.
// ---------------------------------------------------------------------------
__global__ __launch_bounds__(256) void pack_w(const float* __restrict__ W_ih,
                                              const float* __restrict__ W_hh,
                                              unsigned short* __restrict__ WP,
                                              unsigned int* __restrict__ cnt) {
    int e = blockIdx.x * 256 + threadIdx.x;  // 0 .. 327679
    int e8 = e & 7;
    int idx = e >> 3;            // 0..40959
    int row = idx & 255;         // row_local
    int t = idx >> 8;            // 0..159 = (s*4+kseg)*10 + j
    int j = t % 10;
    int sk = t / 10;             // 0..15
    int kseg = sk & 3;
    int s = sk >> 2;
    int kh = kseg * SEGH + j * 8 + e8;
    int gate = row >> 6, unit = row & 63;
    int grow = gate * 256 + s * 64 + unit;   // global gate row
    float v = (kh < 256) ? W_hh[grow * HID + kh] : W_ih[grow * NUM_CH + (kh - 256)];
    HU16 hv;
    hv.h = (_Float16)v;
    WP[e] = hv.u;
    if (blockIdx.x == 0 && threadIdx.x < NGRP) cnt[threadIdx.x] = 0u;
}

// ---------------------------------------------------------------------------
// NMS: rank by score, chunk-serial greedy resolution (wave 0) + parallel apply.
// (unchanged from previous verified version)
// ---------------------------------------------------------------------------
__global__ __launch_bounds__(1024) void nms_kernel(const float* __restrict__ prop,
                                                   int* __restrict__ t0_out) {
    __shared__ float s_sc[NUM_PROP];
    __shared__ float ss[NUM_PROP];
    __shared__ float se[NUM_PROP];
    __shared__ unsigned char sup[NUM_PROP];
    __shared__ unsigned long long cmask[16];

    const int tid = threadIdx.x;
    float ps = prop[tid * 3 + 0];
    float pe = prop[tid * 3 + 1];
    float pc = prop[tid * 3 + 2];
    s_sc[tid] = pc;
    sup[tid] = 0;
    __syncthreads();

    int r = 0;
    for (int j = 0; j < NUM_PROP; ++j) {
        float o = s_sc[j];
        r += (o > pc) || (o == pc && j < tid);
    }
    ss[r] = ps;
    se[r] = pe;
    __syncthreads();

    const float my_s = ss[tid];
    const float my_e = se[tid];
    const float my_len = my_e - my_s;
    bool mysup = false;

    for (int ci = 0; ci < 16; ++ci) {
        if (tid < 64) {
            int i = ci * 64 + tid;
            float is_ = ss[i], ie_ = se[i];
            unsigned long long m = __ballot(sup[i] != 0);
            for (int l = 0; l < 64; ++l) {
                if (!((m >> l) & 1)) {
                    float ls = __shfl(is_, l);
                    float le = __shfl(ie_, l);
                    float inter = fmaxf(fminf(le, ie_) - fmaxf(ls, is_), 0.0f);
                    float uni = (le - ls) + (ie_ - is_) - inter;
                    float iou = inter / fmaxf(uni, 1e-6f);
                    unsigned long long nb = __ballot((tid > l) && (iou > 0.5f));
                    m |= nb;
                }
            }
            sup[i] = (unsigned char)((m >> tid) & 1);
            if (tid == 0) cmask[ci] = ~m;
        }
        __syncthreads();
        unsigned long long am = cmask[ci];
        for (int l = 0; l < 64; ++l) {
            if ((am >> l) & 1) {
                int i = ci * 64 + l;
                if (tid > i && !mysup) {
                    float ls = ss[i], le = se[i];
                    float inter = fmaxf(fminf(le, my_e) - fmaxf(ls, my_s), 0.0f);
                    float uni = (le - ls) + my_len - inter;
                    if (inter / fmaxf(uni, 1e-6f) > 0.5f) mysup = true;
                }
            }
        }
        sup[tid] = mysup ? 1 : 0;
        __syncthreads();
    }

    int myc = tid >> 6;
    unsigned long long mybit = 1ull << (tid & 63);
    int kb = 0, kt = 0;
    for (int c2 = 0; c2 < 16; ++c2) {
        int p = __popcll(cmask[c2]);
        kt += p;
        if (c2 < myc) kb += p;
    }
    kb += __popcll(cmask[myc] & (mybit - 1));
    int slot = (cmask[myc] & mybit) ? kb : (kt + (tid - kb));
    if (slot < NUM_PROP_AFTER) {
        int t0 = (int)rintf(my_s);
        t0 = max(0, min(t0, T_LEN - PROP_LEN));
        t0_out[slot] = t0;
    }
}

// ---------------------------------------------------------------------------
// LSTM: 256 blocks (4 hid-slices x 64 seq-groups), W slice held in VGPRs.
// Per step: lane-uniform broadcast LDS reads of h/x, 160 v_dot2/thread,
// 4-way kseg reduce, activation, h-slice exchange via agent-scope atomics.
// Blocks of a group are stride-64 (same XCD under round-robin dispatch).
// ---------------------------------------------------------------------------
__global__ __launch_bounds__(1024, 4) void lstm_kernel(
    const float* __restrict__ data, const int* __restrict__ t0s,
    const unsigned short* __restrict__ WP,
    const float* __restrict__ b_ih, const float* __restrict__ b_hh,
    const float* __restrict__ W_cls, const float* __restrict__ b_cls,
    const float* __restrict__ W_bbox, const float* __restrict__ b_bbox,
    float* __restrict__ out, unsigned int* __restrict__ Hx,
    unsigned int* __restrict__ cnt) {
    __shared__ __align__(16) _Float16 hx[MS][KH];  // 2.5 KB: [seq][0..255]=h, [256..319]=x
    __shared__ float pp[KSEGN][256][MS];           // 16 KB partial sums
    __shared__ float gsum[256][MS];                // 4 KB gate values
    __shared__ _Float16 hpub[MS][64];              // 512 B h-slice staging

    const int tid = threadIdx.x;
    const int bid = blockIdx.x;
    const int g = bid & 63;   // sequence group
    const int s = bid >> 6;   // hidden slice (units [64s, 64s+64))
    const int kseg = tid >> 8;   // wave-uniform: lanes of a wave share kseg
    const int rl = tid & 255;    // row_local = gate*64 + unit

    // --- W fragment: 10 x uint4 = 80 halves of row (s,rl), segment kseg ---
    uint4 Wr[10];
    {
        const uint4* wp4 = (const uint4*)WP;
        int base = ((s * 4 + kseg) * 10) * 256 + rl;
#pragma unroll
        for (int j = 0; j < 10; ++j) Wr[j] = wp4[base + j * 256];
    }

    // reducer role: thread = (row_local rl2, seq sq2)
    const int rl2 = tid >> 2;
    const int sq2 = tid & 3;
    const int grow2 = (rl2 >> 6) * 256 + s * 64 + (rl2 & 63);
    const float bias_r = b_ih[grow2] + b_hh[grow2];

    // activation role (tid<256): (unit au, seq aq) of this slice
    const int au = tid >> 2;
    const int aq = tid & 3;
    float c_st = 0.0f;

    // x loader role (tid<256): (seq xs, channel xch)
    const int xs = tid >> 6;
    const int xch = tid & 63;
    int xt0 = 0;
    if (tid < 256) xt0 = t0s[g * MS + xs];

    for (int t = 0; t < PROP_LEN; ++t) {
        // x for this step (independent of h -> overlaps the wait)
        if (tid < 256) hx[xs][256 + xch] = (_Float16)data[(xt0 + t) * NUM_CH + xch];

        if (t == 0) {
            hx[tid >> 8][tid & 255] = (_Float16)0.0f;  // h_0 = 0
        } else {
            if (tid == 0) {
                unsigned int tgt = 4u * (unsigned int)t;
                while (__hip_atomic_load(&cnt[g], __ATOMIC_RELAXED,
                                         __HIP_MEMORY_SCOPE_AGENT) < tgt) {
                    __builtin_amdgcn_s_sleep(1);
                }
                __builtin_amdgcn_fence(__ATOMIC_ACQUIRE, "agent");
            }
            __syncthreads();
            if (tid < 512) {  // gather full h_t: 4 seq x 128 u32
                int sq = tid >> 7, w = tid & 127;
                unsigned int v = __hip_atomic_load(
                    &Hx[(((t & 1) * NGRP + g) * MS + sq) * 128 + w],
                    __ATOMIC_RELAXED, __HIP_MEMORY_SCOPE_AGENT);
                ((unsigned int*)hx)[sq * 160 + w] = v;  // row = 160 u32 (320 halves)
            }
        }
        __syncthreads();

        // --- dot: 4 independent accumulator chains, broadcast h reads ---
        float a0 = 0.0f, a1 = 0.0f, a2 = 0.0f, a3 = 0.0f;
#pragma unroll
        for (int j = 0; j < 10; ++j) {
            const int hb = kseg * SEGH + j * 8;
            uint4 h0 = *(const uint4*)&hx[0][hb];
            uint4 h1 = *(const uint4*)&hx[1][hb];
            uint4 h2 = *(const uint4*)&hx[2][hb];
            uint4 h3 = *(const uint4*)&hx[3][hb];
            uint4 w = Wr[j];
            a0 = dot8f(w, h0, a0);
            a1 = dot8f(w, h1, a1);
            a2 = dot8f(w, h2, a2);
            a3 = dot8f(w, h3, a3);
        }
        *(float4*)&pp[kseg][rl][0] = make_float4(a0, a1, a2, a3);
        __syncthreads();

        // --- kseg reduce + bias ---
        gsum[rl2][sq2] = pp[0][rl2][sq2] + pp[1][rl2][sq2] + pp[2][rl2][sq2] +
                         pp[3][rl2][sq2] + bias_r;
        __syncthreads();

        // --- activation + cell update (tid<256) ---
        if (tid < 256) {
            float gi = fsigmoid(gsum[au][aq]);
            float gf = fsigmoid(gsum[64 + au][aq]);
            float gg = ftanh(gsum[128 + au][aq]);
            float go = fsigmoid(gsum[192 + au][aq]);
            c_st = gf * c_st + gi * gg;
            float h = go * ftanh(c_st);
            hpub[aq][au] = (_Float16)h;
        }
        __syncthreads();

        // --- publish h slice (4 seq x 32 u32) to the other buffer ---
        if (tid < 128) {
            int sq = tid >> 5, w = tid & 31;
            unsigned int v = ((const unsigned int*)hpub)[sq * 32 + w];
            __hip_atomic_store(
                &Hx[((((t + 1) & 1) * NGRP + g) * MS + sq) * 128 + (s * 32 + w)], v,
                __ATOMIC_RELAXED, __HIP_MEMORY_SCOPE_AGENT);
        }
        __syncthreads();
        if (tid == 0)
            __hip_atomic_fetch_add(&cnt[g], 1u, __ATOMIC_RELEASE,
                                   __HIP_MEMORY_SCOPE_AGENT);
    }

    // --- heads: wait for all slices' final h (in buffer 0), gather, compute ---
    if (tid == 0) {
        while (__hip_atomic_load(&cnt[g], __ATOMIC_RELAXED,
                                 __HIP_MEMORY_SCOPE_AGENT) < 4u * (unsigned)PROP_LEN) {
            __builtin_amdgcn_s_sleep(1);
        }
        __builtin_amdgcn_fence(__ATOMIC_ACQUIRE, "agent");
    }
    __syncthreads();
    if (tid < 512) {
        int sq = tid >> 7, w = tid & 127;
        unsigned int v = __hip_atomic_load(&Hx[(g * MS + sq) * 128 + w],
                                           __ATOMIC_RELAXED, __HIP_MEMORY_SCOPE_AGENT);
        ((unsigned int*)hx)[sq * 160 + w] = v;
    }
    __syncthreads();

    // slice s computes output rows m in [30s, 30s+30) for its group's 4 seqs
    if (tid < MS * 30) {
        int sq = tid / 30;
        int ml = tid % 30;
        int m = s * 30 + ml;
        const float* Wrow;
        float acc;
        int oidx;
        if (m < NUM_CLS) {
            Wrow = W_cls + m * HID;
            acc = b_cls[m];
            oidx = (g * MS + sq) * NUM_CLS + m;
        } else {
            int mb = m - NUM_CLS;
            Wrow = W_bbox + mb * HID;
            acc = b_bbox[mb];
            oidx = NUM_PROP_AFTER * NUM_CLS + (g * MS + sq) * 2 * NUM_CLS + mb;
        }
        const float4* w4 = (const float4*)Wrow;
        const _Float16* hp = &hx[sq][0];
        for (int c = 0; c < 32; ++c) {
            float4 wa = w4[c * 2 + 0];
            float4 wb = w4[c * 2 + 1];
            acc += (float)hp[c * 8 + 0] * wa.x + (float)hp[c * 8 + 1] * wa.y +
                   (float)hp[c * 8 + 2] * wa.z + (float)hp[c * 8 + 3] * wa.w +
                   (float)hp[c * 8 + 4] * wb.x + (float)hp[c * 8 + 5] * wb.y +
                   (float)hp[c * 8 + 6] * wb.z + (float)hp[c * 8 + 7] * wb.w;
        }
        out[oidx] = acc;
    }
}

extern "C" void kernel_launch(void* const* d_in, const int* in_sizes, int n_in,
                              void* d_out, int out_size, void* d_ws,
                              size_t ws_size, hipStream_t stream) {
    const float* data = (const float*)d_in[0];     // [8192, 64]
    const float* prop = (const float*)d_in[1];     // [1024, 3]
    const float* W_ih = (const float*)d_in[2];     // [1024, 64]
    const float* W_hh = (const float*)d_in[3];     // [1024, 256]
    const float* b_ih = (const float*)d_in[4];     // [1024]
    const float* b_hh = (const float*)d_in[5];     // [1024]
    const float* W_cls = (const float*)d_in[6];    // [40, 256]
    const float* b_cls = (const float*)d_in[7];    // [40]
    const float* W_bbox = (const float*)d_in[8];   // [80, 256]
    const float* b_bbox = (const float*)d_in[9];   // [80]
    float* out = (float*)d_out;

    // workspace layout
    int* t0s = (int*)d_ws;                                         // 1 KB
    unsigned short* WP = (unsigned short*)((char*)d_ws + 1024);    // 640 KB f16
    unsigned int* Hx = (unsigned int*)((char*)d_ws + 656384);      // 256 KB exchange
    unsigned int* cnt = (unsigned int*)((char*)d_ws + 918528);     // 256 B counters

    pack_w<<<1280, 256, 0, stream>>>(W_ih, W_hh, WP, cnt);
    nms_kernel<<<1, 1024, 0, stream>>>(prop, t0s);

    void* kargs[] = {(void*)&data, (void*)&t0s,    (void*)&WP,    (void*)&b_ih,
                     (void*)&b_hh, (void*)&W_cls,  (void*)&b_cls, (void*)&W_bbox,
                     (void*)&b_bbox, (void*)&out,  (void*)&Hx,    (void*)&cnt};
    hipLaunchCooperativeKernel((void*)lstm_kernel, dim3(NSL * NGRP), dim3(1024),
                               kargs, 0, stream);
}

// Round 2
// 740.108 us; speedup vs baseline: 1.7149x; 1.7030x over previous
//
#include <hip/hip_runtime.h>
#include <math.h>

#define T_LEN 8192
#define NUM_CH 64
#define HID 256
#define NUM_CLS 40
#define NUM_PROP 1024
#define NUM_PROP_AFTER 256
#define PROP_LEN 128

#define MS 4        // sequences per group
#define NGRP 64     // sequence groups (NUM_PROP_AFTER / MS)
#define NSL 4       // hidden slices (64 units each)
#define KH 320      // K in halves: 256 h + 64 x
#define KSEGN 4     // K segments per row
#define SEGH 80     // halves per segment

typedef _Float16 h2_t __attribute__((ext_vector_type(2)));
union U32H2 { unsigned int u; h2_t h; };
union HU16 { _Float16 h; unsigned short u; };

#if defined(__has_builtin)
#if __has_builtin(__builtin_amdgcn_fdot2)
#define HAS_FDOT2 1
#endif
#endif

__device__ __forceinline__ float dot2f(unsigned int wa, unsigned int hb, float acc) {
    U32H2 a, b;
    a.u = wa;
    b.u = hb;
#ifdef HAS_FDOT2
    return __builtin_amdgcn_fdot2(a.h, b.h, acc, false);
#else
    return acc + (float)a.h[0] * (float)b.h[0] + (float)a.h[1] * (float)b.h[1];
#endif
}

__device__ __forceinline__ float dot8f(const uint4& w, const uint4& h, float acc) {
    acc = dot2f(w.x, h.x, acc);
    acc = dot2f(w.y, h.y, acc);
    acc = dot2f(w.z, h.z, acc);
    acc = dot2f(w.w, h.w, acc);
    return acc;
}

__device__ __forceinline__ float fsigmoid(float x) { return 1.0f / (1.0f + __expf(-x)); }
__device__ __forceinline__ float ftanh(float x) {
    float e = __expf(-2.0f * fabsf(x));
    float t = (1.0f - e) / (1.0f + e);
    return copysignf(t, x);
}

// ---------------------------------------------------------------------------
// Pack W into f16, per-(slice,kseg) register-fragment layout:
// uint4 index = ((s*4 + kseg)*10 + j)*256 + row_local   (row_local = gate*64+unit)
// half e8 in uint4 covers kh = kseg*80 + j*8 + e8; kh<256 -> W_hh, else W_ih.
// Also zeroes the per-group sync counters (padded to 64B each).
// ---------------------------------------------------------------------------
__global__ __launch_bounds__(256) void pack_w(const float* __restrict__ W_ih,
                                              const float* __restrict__ W_hh,
                                              unsigned short* __restrict__ WP,
                                              unsigned int* __restrict__ cnt) {
    int e = blockIdx.x * 256 + threadIdx.x;  // 0 .. 327679
    int e8 = e & 7;
    int idx = e >> 3;            // 0..40959
    int row = idx & 255;         // row_local
    int t = idx >> 8;            // 0..159 = (s*4+kseg)*10 + j
    int j = t % 10;
    int sk = t / 10;             // 0..15
    int kseg = sk & 3;
    int s = sk >> 2;
    int kh = kseg * SEGH + j * 8 + e8;
    int gate = row >> 6, unit = row & 63;
    int grow = gate * 256 + s * 64 + unit;   // global gate row
    float v = (kh < 256) ? W_hh[grow * HID + kh] : W_ih[grow * NUM_CH + (kh - 256)];
    HU16 hv;
    hv.h = (_Float16)v;
    WP[e] = hv.u;
    if (blockIdx.x == 0 && threadIdx.x < NGRP) cnt[threadIdx.x * 16] = 0u;
}

// ---------------------------------------------------------------------------
// NMS: rank by score, chunk-serial greedy resolution (wave 0) + parallel apply.
// (unchanged from previous verified version)
// ---------------------------------------------------------------------------
__global__ __launch_bounds__(1024) void nms_kernel(const float* __restrict__ prop,
                                                   int* __restrict__ t0_out) {
    __shared__ float s_sc[NUM_PROP];
    __shared__ float ss[NUM_PROP];
    __shared__ float se[NUM_PROP];
    __shared__ unsigned char sup[NUM_PROP];
    __shared__ unsigned long long cmask[16];

    const int tid = threadIdx.x;
    float ps = prop[tid * 3 + 0];
    float pe = prop[tid * 3 + 1];
    float pc = prop[tid * 3 + 2];
    s_sc[tid] = pc;
    sup[tid] = 0;
    __syncthreads();

    int r = 0;
    for (int j = 0; j < NUM_PROP; ++j) {
        float o = s_sc[j];
        r += (o > pc) || (o == pc && j < tid);
    }
    ss[r] = ps;
    se[r] = pe;
    __syncthreads();

    const float my_s = ss[tid];
    const float my_e = se[tid];
    const float my_len = my_e - my_s;
    bool mysup = false;

    for (int ci = 0; ci < 16; ++ci) {
        if (tid < 64) {
            int i = ci * 64 + tid;
            float is_ = ss[i], ie_ = se[i];
            unsigned long long m = __ballot(sup[i] != 0);
            for (int l = 0; l < 64; ++l) {
                if (!((m >> l) & 1)) {
                    float ls = __shfl(is_, l);
                    float le = __shfl(ie_, l);
                    float inter = fmaxf(fminf(le, ie_) - fmaxf(ls, is_), 0.0f);
                    float uni = (le - ls) + (ie_ - is_) - inter;
                    float iou = inter / fmaxf(uni, 1e-6f);
                    unsigned long long nb = __ballot((tid > l) && (iou > 0.5f));
                    m |= nb;
                }
            }
            sup[i] = (unsigned char)((m >> tid) & 1);
            if (tid == 0) cmask[ci] = ~m;
        }
        __syncthreads();
        unsigned long long am = cmask[ci];
        for (int l = 0; l < 64; ++l) {
            if ((am >> l) & 1) {
                int i = ci * 64 + l;
                if (tid > i && !mysup) {
                    float ls = ss[i], le = se[i];
                    float inter = fmaxf(fminf(le, my_e) - fmaxf(ls, my_s), 0.0f);
                    float uni = (le - ls) + my_len - inter;
                    if (inter / fmaxf(uni, 1e-6f) > 0.5f) mysup = true;
                }
            }
        }
        sup[tid] = mysup ? 1 : 0;
        __syncthreads();
    }

    int myc = tid >> 6;
    unsigned long long mybit = 1ull << (tid & 63);
    int kb = 0, kt = 0;
    for (int c2 = 0; c2 < 16; ++c2) {
        int p = __popcll(cmask[c2]);
        kt += p;
        if (c2 < myc) kb += p;
    }
    kb += __popcll(cmask[myc] & (mybit - 1));
    int slot = (cmask[myc] & mybit) ? kb : (kt + (tid - kb));
    if (slot < NUM_PROP_AFTER) {
        int t0 = (int)rintf(my_s);
        t0 = max(0, min(t0, T_LEN - PROP_LEN));
        t0_out[slot] = t0;
    }
}

// ---------------------------------------------------------------------------
// LSTM: 256 blocks (4 hid-slices x 64 seq-groups), W slice held in VGPRs.
// Exchange protocol: ALL cross-block traffic is relaxed agent-scope atomics
// (sc0|sc1, cache-bypassing) -- no release/acquire fences, so no buffer_wbl2 /
// buffer_inv L2 maintenance. Ordering: producer waves drain their own stores
// (s_waitcnt vmcnt(0)) before the relaxed counter add; consumers poll the
// counter, barrier, then issue cache-bypassing gathers.
// 3 barriers per step; x-prefetch overlapped with epilogue on idle waves.
// ---------------------------------------------------------------------------
__global__ __launch_bounds__(1024, 4) void lstm_kernel(
    const float* __restrict__ data, const int* __restrict__ t0s,
    const unsigned short* __restrict__ WP,
    const float* __restrict__ b_ih, const float* __restrict__ b_hh,
    const float* __restrict__ W_cls, const float* __restrict__ b_cls,
    const float* __restrict__ W_bbox, const float* __restrict__ b_bbox,
    float* __restrict__ out, unsigned int* __restrict__ Hx,
    unsigned int* __restrict__ cnt) {
    __shared__ __align__(16) _Float16 hx[MS][KH];  // 2.5 KB: [seq][0..255]=h, [256..319]=x
    __shared__ float pp[MS][KSEGN][256];           // 16 KB partial sums

    const int tid = threadIdx.x;
    const int g = blockIdx.x & (NGRP - 1);  // sequence group
    const int s = blockIdx.x >> 6;          // hidden slice (units [64s, 64s+64))
    const int kseg = tid >> 8;              // wave-uniform K segment
    const int rl = tid & 255;               // row_local = gate*64 + unit

    // --- W fragment: 10 x uint4 = 80 halves of row (s,rl), segment kseg ---
    uint4 Wr[10];
    {
        const uint4* wp4 = (const uint4*)WP;
        int base = ((s * 4 + kseg) * 10) * 256 + rl;
#pragma unroll
        for (int j = 0; j < 10; ++j) Wr[j] = wp4[base + j * 256];
    }

    // epilogue role (tid<256): wave aq handles seq aq, lane au = unit
    const int aq = tid >> 6;
    const int au = tid & 63;
    float bi = 0.f, bf = 0.f, bg = 0.f, bo = 0.f, c_st = 0.f;
    if (tid < 256) {
        int u = s * 64 + au;
        bi = b_ih[u] + b_hh[u];
        bf = b_ih[256 + u] + b_hh[256 + u];
        bg = b_ih[512 + u] + b_hh[512 + u];
        bo = b_ih[768 + u] + b_hh[768 + u];
    }

    // x-prefetch role (waves 8-11): (seq xs, channel xch)
    const int xs = (tid >> 6) & 3;
    const int xch = tid & 63;
    const bool xrole = (tid >= 512 && tid < 768);
    int xt0 = 0;
    if (xrole) {
        xt0 = t0s[g * MS + xs];
        hx[xs][256 + xch] = (_Float16)data[xt0 * NUM_CH + xch];  // x(0)
    }
    // zero h region: 1024 threads x 1 half
    hx[tid >> 8][tid & 255] = (_Float16)0.0f;

    unsigned short* HxH = (unsigned short*)Hx;
    unsigned int* cg = &cnt[g * 16];
    __syncthreads();  // doubles as pre-dot barrier for t=0

    for (int t = 0; t < PROP_LEN; ++t) {
        // --- dot: 4 independent accumulator chains, broadcast LDS reads ---
        float a0 = 0.f, a1 = 0.f, a2 = 0.f, a3 = 0.f;
#pragma unroll
        for (int j = 0; j < 10; ++j) {
            const int hb = kseg * SEGH + j * 8;
            uint4 h0 = *(const uint4*)&hx[0][hb];
            uint4 h1 = *(const uint4*)&hx[1][hb];
            uint4 h2 = *(const uint4*)&hx[2][hb];
            uint4 h3 = *(const uint4*)&hx[3][hb];
            uint4 w = Wr[j];
            a0 = dot8f(w, h0, a0);
            a1 = dot8f(w, h1, a1);
            a2 = dot8f(w, h2, a2);
            a3 = dot8f(w, h3, a3);
        }
        pp[0][kseg][rl] = a0;
        pp[1][kseg][rl] = a1;
        pp[2][kseg][rl] = a2;
        pp[3][kseg][rl] = a3;
        __syncthreads();

        // --- fused reduce + activation + publish (waves 0-3) ---
        if (tid < 256) {
            float si = pp[aq][0][au] + pp[aq][1][au] + pp[aq][2][au] +
                       pp[aq][3][au] + bi;
            float sf = pp[aq][0][64 + au] + pp[aq][1][64 + au] +
                       pp[aq][2][64 + au] + pp[aq][3][64 + au] + bf;
            float sg = pp[aq][0][128 + au] + pp[aq][1][128 + au] +
                       pp[aq][2][128 + au] + pp[aq][3][128 + au] + bg;
            float so = pp[aq][0][192 + au] + pp[aq][1][192 + au] +
                       pp[aq][2][192 + au] + pp[aq][3][192 + au] + bo;
            float gi = fsigmoid(si), gf = fsigmoid(sf);
            float gg = ftanh(sg), go = fsigmoid(so);
            c_st = gf * c_st + gi * gg;
            float h = go * ftanh(c_st);
            HU16 hu;
            hu.h = (_Float16)h;
            __hip_atomic_store(
                &HxH[((((t + 1) & 1) * NGRP + g) * MS + aq) * 256 + s * 64 + au],
                hu.u, __ATOMIC_RELAXED, __HIP_MEMORY_SCOPE_AGENT);
            // wave-local drain: stores acked at coherence point before the add
            asm volatile("s_waitcnt vmcnt(0)" ::: "memory");
            if (au == 0)
                __hip_atomic_fetch_add(cg, 1u, __ATOMIC_RELAXED,
                                       __HIP_MEMORY_SCOPE_AGENT);
        } else if (xrole && t + 1 < PROP_LEN) {
            // prefetch x(t+1) on otherwise-idle waves (x region not read here)
            hx[xs][256 + xch] = (_Float16)data[(xt0 + t + 1) * NUM_CH + xch];
        }

        // --- wait for all 16 wave-adds of this step, then gather h_{t+1} ---
        const unsigned int tgt = 16u * (unsigned int)(t + 1);
        if (tid == 0) {
            while (__hip_atomic_load(cg, __ATOMIC_RELAXED,
                                     __HIP_MEMORY_SCOPE_AGENT) < tgt) {
                __builtin_amdgcn_s_sleep(1);
            }
        }
        __syncthreads();
        if (tid < 512) {
            int sq = tid >> 7, w = tid & 127;
            unsigned int v = __hip_atomic_load(
                &Hx[((((t + 1) & 1) * NGRP + g) * MS + sq) * 128 + w],
                __ATOMIC_RELAXED, __HIP_MEMORY_SCOPE_AGENT);
            ((unsigned int*)hx)[sq * 160 + w] = v;
        }
        __syncthreads();
    }

    // hx now holds h_128 for all 4 seqs (gathered in the last iteration).
    // slice s computes output rows m in [30s, 30s+30) for its group's 4 seqs
    if (tid < MS * 30) {
        int sq = tid / 30;
        int ml = tid % 30;
        int m = s * 30 + ml;
        const float* Wrow;
        float acc;
        int oidx;
        if (m < NUM_CLS) {
            Wrow = W_cls + m * HID;
            acc = b_cls[m];
            oidx = (g * MS + sq) * NUM_CLS + m;
        } else {
            int mb = m - NUM_CLS;
            Wrow = W_bbox + mb * HID;
            acc = b_bbox[mb];
            oidx = NUM_PROP_AFTER * NUM_CLS + (g * MS + sq) * 2 * NUM_CLS + mb;
        }
        const float4* w4 = (const float4*)Wrow;
        const _Float16* hp = &hx[sq][0];
        for (int c = 0; c < 32; ++c) {
            float4 wa = w4[c * 2 + 0];
            float4 wb = w4[c * 2 + 1];
            acc += (float)hp[c * 8 + 0] * wa.x + (float)hp[c * 8 + 1] * wa.y +
                   (float)hp[c * 8 + 2] * wa.z + (float)hp[c * 8 + 3] * wa.w +
                   (float)hp[c * 8 + 4] * wb.x + (float)hp[c * 8 + 5] * wb.y +
                   (float)hp[c * 8 + 6] * wb.z + (float)hp[c * 8 + 7] * wb.w;
        }
        out[oidx] = acc;
    }
}

extern "C" void kernel_launch(void* const* d_in, const int* in_sizes, int n_in,
                              void* d_out, int out_size, void* d_ws,
                              size_t ws_size, hipStream_t stream) {
    const float* data = (const float*)d_in[0];     // [8192, 64]
    const float* prop = (const float*)d_in[1];     // [1024, 3]
    const float* W_ih = (const float*)d_in[2];     // [1024, 64]
    const float* W_hh = (const float*)d_in[3];     // [1024, 256]
    const float* b_ih = (const float*)d_in[4];     // [1024]
    const float* b_hh = (const float*)d_in[5];     // [1024]
    const float* W_cls = (const float*)d_in[6];    // [40, 256]
    const float* b_cls = (const float*)d_in[7];    // [40]
    const float* W_bbox = (const float*)d_in[8];   // [80, 256]
    const float* b_bbox = (const float*)d_in[9];   // [80]
    float* out = (float*)d_out;

    // workspace layout
    int* t0s = (int*)d_ws;                                         // 1 KB
    unsigned short* WP = (unsigned short*)((char*)d_ws + 1024);    // 640 KB f16
    unsigned int* Hx = (unsigned int*)((char*)d_ws + 656384);      // 256 KB exchange
    unsigned int* cnt = (unsigned int*)((char*)d_ws + 918528);     // 4 KB counters (64B-padded)

    pack_w<<<1280, 256, 0, stream>>>(W_ih, W_hh, WP, cnt);
    nms_kernel<<<1, 1024, 0, stream>>>(prop, t0s);

    void* kargs[] = {(void*)&data, (void*)&t0s,    (void*)&WP,    (void*)&b_ih,
                     (void*)&b_hh, (void*)&W_cls,  (void*)&b_cls, (void*)&W_bbox,
                     (void*)&b_bbox, (void*)&out,  (void*)&Hx,    (void*)&cnt};
    hipLaunchCooperativeKernel((void*)lstm_kernel, dim3(NSL * NGRP), dim3(1024),
                               kargs, 0, stream);
}